// Round 5
// baseline (330.536 us; speedup 1.0000x reference)
//
#include <hip/hip_runtime.h>

#define NBATCH  16
#define COLS_W  256                // columns per wave strip (64 lanes x float4)
#define NSTRIPS (1024 / COLS_W)    // 4
#define SEGROWS 32                 // rows per wave segment
#define NSEGS   (1024 / SEGROWS)   // 32
#define NWAVES  (NBATCH * NSTRIPS * NSEGS)  // 2048
#define NBLOCKS (NWAVES / 4)       // 512 blocks x 4 waves = 2 blocks/CU, 8 waves/CU
#define NHIST   8                  // global histogram copies

__device__ __forceinline__ float gray3(float r, float g, float b) {
    return (r * 0.299f + g * 0.587f) + b * 0.114f;
}

__global__ __launch_bounds__(256, 2) void lbp_hist_kernel(
        const float* __restrict__ img, unsigned* __restrict__ g_hist,
        float* __restrict__ out) {
    __shared__ unsigned s_hist[4][256];               // one copy per wave
    __shared__ float red[256];
    __shared__ int s_last;
    const int tid  = threadIdx.x;
    const int wv   = tid >> 6;
    const int lane = tid & 63;
    #pragma unroll
    for (int i = 0; i < 4; ++i) s_hist[i][tid] = 0u;
    __syncthreads();

    const int w     = blockIdx.x * 4 + wv;            // flat wave id 0..2047
    const int strip = w & (NSTRIPS - 1);              // adjacent waves -> adjacent strips
    const int seg   = (w >> 2) & (NSEGS - 1);
    const int b     = w >> 7;                         // 128 waves per batch image
    const int wx    = strip * COLS_W;
    const int x     = wx + 4 * lane;                  // first of this lane's 4 columns (16B aligned)
    const int y0    = seg * SEGROWS;
    const int ylast = y0 + SEGROWS;                   // deepest row consumed (y0+32)

    const float* R = img + (size_t)b * 3145728u;
    const float* G = R + 1048576;
    const float* B = R + 2097152;

    const bool hL  = (lane == 0);
    const bool hR  = (lane == 63);
    const int  hx  = hL ? (wx - 1) : (wx + COLS_W);   // halo column for edge lanes
    const bool hOk = (hL || hR) && ((unsigned)hx < 1024u);

    // issue: start float4 loads for one image row; zero-fill OOB rows (SAME padding)
    // and rows beyond [y0-1, y0+32] (wave-uniform clamp).
    auto issue = [&](int y, float4& rr, float4& gg, float4& bb,
                     float& hr2, float& hg2, float& hb2) {
        rr = gg = bb = make_float4(0.f, 0.f, 0.f, 0.f);
        hr2 = hg2 = hb2 = 0.f;
        if ((unsigned)y < 1024u && y <= ylast) {
            const int o = y << 10;
            rr = *(const float4*)(R + o + x);
            gg = *(const float4*)(G + o + x);
            bb = *(const float4*)(B + o + x);
            if (hOk) { hr2 = R[o + hx]; hg2 = G[o + hx]; hb2 = B[o + hx]; }
        }
    };
    // finish: gray-convert a landed row into row[6] = {l, c0, c1, c2, c3, r}
    auto finish = [&](const float4& rr, const float4& gg, const float4& bb,
                      float hr2, float hg2, float hb2, float* row) {
        row[1] = gray3(rr.x, gg.x, bb.x);
        row[2] = gray3(rr.y, gg.y, bb.y);
        row[3] = gray3(rr.z, gg.z, bb.z);
        row[4] = gray3(rr.w, gg.w, bb.w);
        const float hh = gray3(hr2, hg2, hb2);        // meaningful only on lanes 0/63
        const float lu = __shfl_up(row[4], 1);        // lane-1's col x-1
        const float rd = __shfl_down(row[1], 1);      // lane+1's col x+4
        row[0] = hL ? hh : lu;                        // col x-1 (0-pad at image edge)
        row[5] = hR ? hh : rd;                        // col x+4 (0-pad at image edge)
    };

    // rolling 3x3 window: r0 = row y-1, r1 = row y, r2 = row y+1 (constant-indexed)
    float r0[6], r1[6], r2[6];
    // depth-2 prefetch: p1 = next consumed row (y+1), p2 = row y+2
    float4 p1r, p1g, p1b;  float p1hr, p1hg, p1hb;
    float4 p2r, p2g, p2b;  float p2hr, p2hg, p2hb;
    float4 nr,  ng,  nb;   float nhr,  nhg,  nhb;

    issue(y0 - 1, p1r, p1g, p1b, p1hr, p1hg, p1hb);
    finish(p1r, p1g, p1b, p1hr, p1hg, p1hb, r0);      // row y0-1
    issue(y0,     p1r, p1g, p1b, p1hr, p1hg, p1hb);
    finish(p1r, p1g, p1b, p1hr, p1hg, p1hb, r1);      // row y0
    issue(y0 + 1, p1r, p1g, p1b, p1hr, p1hg, p1hb);   // p1 = row y0+1 in flight
    issue(y0 + 2, p2r, p2g, p2b, p2hr, p2hg, p2hb);   // p2 = row y0+2 in flight

    unsigned cnt0 = 0u, cnt255 = 0u;

    #pragma unroll 4
    for (int y = y0; y < y0 + SEGROWS; ++y) {
        // keep 2 rows of loads in flight: issue y+3 before waiting on y+1
        issue(y + 3, nr, ng, nb, nhr, nhg, nhb);
        finish(p1r, p1g, p1b, p1hr, p1hg, p1hb, r2);  // row y+1

        // 4 pixels per lane; pixel k center = r1[k+1], neighbors at k / k+1 / k+2
        #pragma unroll
        for (int k = 0; k < 4; ++k) {
            const float c = r1[k + 1];
            const unsigned code =
                (r0[k + 2] >= c ?   1u : 0u) |   // (y-1, x+1)
                (r1[k + 2] >= c ?   2u : 0u) |   // (y,   x+1)
                (r2[k + 2] >= c ?   4u : 0u) |   // (y+1, x+1)
                (r2[k + 1] >= c ?   8u : 0u) |   // (y+1, x  )
                (r2[k]     >= c ?  16u : 0u) |   // (y+1, x-1)
                (r1[k]     >= c ?  32u : 0u) |   // (y,   x-1)
                (r0[k]     >= c ?  64u : 0u) |   // (y-1, x-1)
                (r0[k + 1] >= c ? 128u : 0u);    // (y-1, x  )
            // hot bins (3x3 extremum, ~11% each on uniform data): ballot, no atomic
            cnt0   += (unsigned)__popcll(__ballot(code ==   0u));
            cnt255 += (unsigned)__popcll(__ballot(code == 255u));
            if ((code - 1u) < 254u)              // codes 1..254: near-uniform, low conflict
                atomicAdd(&s_hist[wv][code], 1u);
        }

        #pragma unroll
        for (int i = 0; i < 6; ++i) { r0[i] = r1[i]; r1[i] = r2[i]; }
        p1r = p2r; p1g = p2g; p1b = p2b; p1hr = p2hr; p1hg = p2hg; p1hb = p2hb;
        p2r = nr;  p2g = ng;  p2b = nb;  p2hr = nhr;  p2hg = nhg;  p2hb = nhb;
    }

    if (lane == 0) {                                  // cnt0/cnt255 are wave-uniform
        atomicAdd(&s_hist[wv][0],   cnt0);
        atomicAdd(&s_hist[wv][255], cnt255);
    }
    __syncthreads();
    const unsigned total = s_hist[0][tid] + s_hist[1][tid] + s_hist[2][tid] + s_hist[3][tid];
    atomicAdd(&g_hist[((blockIdx.x & (NHIST - 1)) << 8) + tid], total);

    // ---- fused finalize: last block to finish reduces the copies ----
    __threadfence();                                  // release our flush
    if (tid == 0) {
        const unsigned rank = atomicAdd(&g_hist[NHIST * 256], 1u);
        s_last = (rank == NBLOCKS - 1) ? 1 : 0;
    }
    __syncthreads();
    if (s_last) {
        __threadfence();                              // acquire all flushes
        unsigned hv = 0u;
        #pragma unroll
        for (int c2 = 0; c2 < NHIST; ++c2)
            hv += __hip_atomic_load(&g_hist[(c2 << 8) + tid],
                                    __ATOMIC_RELAXED, __HIP_MEMORY_SCOPE_AGENT);
        const float h = (float)hv;
        red[tid] = h;
        __syncthreads();
        #pragma unroll
        for (int s = 128; s > 0; s >>= 1) {
            if (tid < s) red[tid] += red[tid + s];
            __syncthreads();
        }
        const float mean = red[0] * (1.0f / 256.0f);
        __syncthreads();
        const float d = h - mean;
        red[tid] = d * d;
        __syncthreads();
        #pragma unroll
        for (int s = 128; s > 0; s >>= 1) {
            if (tid < s) red[tid] += red[tid + s];
            __syncthreads();
        }
        out[tid] = d / sqrtf(red[0] * (1.0f / 255.0f));
    }
}

extern "C" void kernel_launch(void* const* d_in, const int* in_sizes, int n_in,
                              void* d_out, int out_size, void* d_ws, size_t ws_size,
                              hipStream_t stream) {
    const float* img = (const float*)d_in[0];
    unsigned* g_hist = (unsigned*)d_ws;   // NHIST*256 bins + completion counter
    float* out = (float*)d_out;

    // zero hist copies + completion counter (graph-capture-safe, re-zeroed every replay)
    hipMemsetAsync(g_hist, 0, (NHIST * 256 + 4) * sizeof(unsigned), stream);
    lbp_hist_kernel<<<NBLOCKS, 256, 0, stream>>>(img, g_hist, out);
}